// Round 3
// baseline (390.705 us; speedup 1.0000x reference)
//
#include <hip/hip_runtime.h>

typedef _Float16 f16;
typedef _Float16 h8_t __attribute__((ext_vector_type(8)));
typedef _Float16 h4_t __attribute__((ext_vector_type(4)));
typedef float f32x4 __attribute__((ext_vector_type(4)));
typedef float f32x16 __attribute__((ext_vector_type(16)));

#define BS 16
#define DA 512
#define SL 1024
#define NH 8
#define DH 64

// direct global->LDS DMA, 16B per lane. HW dest = wave-uniform base + lane*16,
// so lane i's lds pointer must equal base + i*16 (linear layout).
__device__ __forceinline__ void gload_lds16(const void* g, void* l) {
  __builtin_amdgcn_global_load_lds((const __attribute__((address_space(1))) void*)g,
                                   (__attribute__((address_space(3))) void*)l, 16, 0, 0);
}

// ---------------------------------------------------------------------------
// P0: prep pass (unchanged).
//  blocks [0,2048):   transpose+convert X [b][c][s] f32 -> Xt [b][s][c] f16
//  blocks [2048,2112): convert k_w / v_w f32 -> f16
// ---------------------------------------------------------------------------
__global__ __launch_bounds__(256) void prep_kernel(
    const float* __restrict__ k_in, const float* __restrict__ v_in,
    const float* __restrict__ k_w, const float* __restrict__ v_w,
    f16* __restrict__ Kt, f16* __restrict__ Vt,
    f16* __restrict__ kwh, f16* __restrict__ vwh) {
  const int blk = blockIdx.x;
  const int t = threadIdx.x;
  if (blk < 2048) {
    const int which = blk >> 10;        // 0: k_in, 1: v_in
    const int r = blk & 1023;
    const int b = r >> 6;               // 0..15
    const int c0 = ((r >> 3) & 7) * 64; // 8 c-tiles
    const int s0 = (r & 7) * 128;       // 8 s-tiles
    const float* src = which ? v_in : k_in;
    f16* dst = which ? Vt : Kt;
    __shared__ __align__(16) float Xf32[64 * 132];
#pragma unroll
    for (int p = 0; p < 8; ++p) {
      const int idx = p * 256 + t;
      const int cc = idx >> 5, s4 = (idx & 31) * 4;
      const float4 v = *(const float4*)&src[((size_t)b * DA + c0 + cc) * SL + s0 + s4];
      *(float4*)&Xf32[cc * 132 + s4] = v;
    }
    __syncthreads();
    const int srow = t >> 1, cb = (t & 1) * 32;
#pragma unroll
    for (int g = 0; g < 4; ++g) {
      h8_t h;
#pragma unroll
      for (int u = 0; u < 8; ++u) h[u] = (f16)Xf32[(cb + g * 8 + u) * 132 + srow];
      *(h8_t*)&dst[((size_t)b * SL + s0 + srow) * DA + c0 + cb + g * 8] = h;
    }
  } else {
    const int r = blk - 2048;           // 0..63
    const int wsel = r >> 5;            // 0: k_w, 1: v_w
    const float* src = wsel ? v_w : k_w;
    f16* dst = wsel ? vwh : kwh;
    const int base = (r & 31) * 8192;
#pragma unroll
    for (int p = 0; p < 4; ++p) {
      const int i = base + p * 2048 + t * 8;
      const float4 a = *(const float4*)&src[i];
      const float4 c = *(const float4*)&src[i + 4];
      h8_t h;
      h[0] = (f16)a.x; h[1] = (f16)a.y; h[2] = (f16)a.z; h[3] = (f16)a.w;
      h[4] = (f16)c.x; h[5] = (f16)c.y; h[6] = (f16)c.z; h[7] = (f16)c.w;
      *(h8_t*)&dst[i] = h;
    }
  }
}

// ---------------------------------------------------------------------------
// K1: projection GEMM v2 — LDS-resident WEIGHT, global-streamed activation.
// W chunk [128 o][128 c] (32 KB) staged 4x per block via gload_lds with
// pre-swizzled SOURCE (rule #21: linear dest, XOR byte^=((row&7)<<4) on read);
// activation fragments (8 contiguous f16 = 16B) loaded straight from global:
// no per-K-step staging, NO barriers inside the K-loop (8 barriers/block).
// grid (32, BS, 2) = 1024 blocks = 4/CU.
// mode 0: A=W (m=o), B=Kt[b] (n=s)  -> kp[b][s][o] + k_b(m)
// mode 1: A=Vt[b] (m=s), B=W (n=o)  -> vp[b][o][s] + v_b(n)
// Epilogue identical to the verified R1/R2 one.
// ---------------------------------------------------------------------------
__global__ __launch_bounds__(256, 4) void proj_gemm_all(
    const f16* __restrict__ kwh, const f16* __restrict__ vwh,
    const f16* __restrict__ Kt, const f16* __restrict__ Vt,
    const float* __restrict__ k_b, const float* __restrict__ v_b,
    f16* __restrict__ kp, f16* __restrict__ vp) {
  __shared__ __align__(16) f16 Wl[128 * 128];  // 32 KB, swizzled layout
  const int mode = blockIdx.z;
  const int b = blockIdx.y;
  const int tx = blockIdx.x;
  const int ot = tx & 3, st = tx >> 2;         // o-tile (W side), s-tile (X side)
  const int oo = ot * 128, ss = st * 128;
  const int m0 = mode ? ss : oo;
  const int n0 = mode ? oo : ss;
  const int t = threadIdx.x;
  const int lane = t & 63, w = t >> 6, lr = lane & 15, lq = lane >> 4;
  const int wm = (w >> 1) * 64, wn = (w & 1) * 64;

  const f16* Wg = (mode ? vwh : kwh) + (size_t)oo * DA;
  const f16* Xg = (mode ? Vt : Kt) + (size_t)b * SL * DA + (size_t)ss * DA;
  const int xw = mode ? wm : wn;  // X-side wave offset (m in mode1, n in mode0)
  const int ww = mode ? wn : wm;  // W-side wave offset

  f32x4 acc[4][4] = {};

  // stage W quarter 0 (source pre-swizzled so linear DMA + swizzled read agree)
#pragma unroll
  for (int p = 0; p < 8; ++p) {
    const int S = p * 4096 + t * 16;                  // LDS byte slot
    const int u = (S ^ (((S >> 8) & 7) << 4)) >> 1;   // logical f16 index
    gload_lds16(&Wg[(size_t)(u >> 7) * DA + (u & 127)], (char*)Wl + S);
  }
  __syncthreads();

  for (int q = 0; q < 4; ++q) {
    const int c0 = q * 128;
#pragma unroll
    for (int ks = 0; ks < 4; ++ks) {
      h8_t xf[4], wf[4];
#pragma unroll
      for (int e = 0; e < 4; ++e) {
        const int xrow = xw + e * 16 + lr;
        xf[e] = *(const h8_t*)&Xg[(size_t)xrow * DA + c0 + ks * 32 + lq * 8];
        const int wrow = ww + e * 16 + lr;
        const int ba = (wrow << 8) + ks * 64 + lq * 16;
        wf[e] = *(const h8_t*)((const char*)Wl + (ba ^ ((wrow & 7) << 4)));
      }
      __builtin_amdgcn_s_setprio(1);
      if (mode == 0) {
#pragma unroll
        for (int i = 0; i < 4; ++i)
#pragma unroll
          for (int j = 0; j < 4; ++j)
            acc[i][j] = __builtin_amdgcn_mfma_f32_16x16x32_f16(wf[i], xf[j], acc[i][j], 0, 0, 0);
      } else {
#pragma unroll
        for (int i = 0; i < 4; ++i)
#pragma unroll
          for (int j = 0; j < 4; ++j)
            acc[i][j] = __builtin_amdgcn_mfma_f32_16x16x32_f16(xf[i], wf[j], acc[i][j], 0, 0, 0);
      }
      __builtin_amdgcn_s_setprio(0);
    }
    if (q < 3) {
      __syncthreads();  // all waves done reading this W chunk
      const int cn = (q + 1) * 128;
#pragma unroll
      for (int p = 0; p < 8; ++p) {
        const int S = p * 4096 + t * 16;
        const int u = (S ^ (((S >> 8) & 7) << 4)) >> 1;
        gload_lds16(&Wg[(size_t)(u >> 7) * DA + cn + (u & 127)], (char*)Wl + S);
      }
      __syncthreads();  // DMA drained: next chunk resident
    }
  }

  // epilogue: D row = gm (4 consecutive per lane -> 8B f16 stores), col = gn
#pragma unroll
  for (int i = 0; i < 4; ++i) {
    const int gmb = m0 + wm + i * 16 + lq * 4;
    float bm[4] = {0.f, 0.f, 0.f, 0.f};
    if (mode == 0) {
      const float4 b4 = *(const float4*)&k_b[gmb];
      bm[0] = b4.x; bm[1] = b4.y; bm[2] = b4.z; bm[3] = b4.w;
    }
#pragma unroll
    for (int j = 0; j < 4; ++j) {
      const int gn = n0 + wn + j * 16 + lr;
      const float bn = mode ? v_b[gn] : 0.f;
      h4_t hv;
#pragma unroll
      for (int r = 0; r < 4; ++r) {
        const float val = acc[i][j][r] + (mode == 0 ? bm[r] : bn);
        hv[r] = (f16)val;
      }
      f16* dst = mode ? &vp[((size_t)b * DA + gn) * SL + gmb]
                      : &kp[((size_t)b * SL + gn) * DA + gmb];
      *(h4_t*)dst = hv;
    }
  }
}

// ---------------------------------------------------------------------------
// Fallback: fused transpose+projection kernel (small-workspace path only).
// ---------------------------------------------------------------------------
template <int MODE>
__global__ __launch_bounds__(256) void fused_proj(const float* __restrict__ Wg,
                                                  const float* __restrict__ Xin,
                                                  const float* __restrict__ bias,
                                                  f16* __restrict__ outg) {
  constexpr int MT = MODE ? SL : DA;
  constexpr int NT = MODE ? DA : SL;
  __shared__ f16 Wl[128 * 40];
  __shared__ f16 Xl[128 * 40];
  __shared__ float Xf32[32 * 132];
  const int b = blockIdx.z;
  const int m0 = blockIdx.x * 128;
  const int n0 = blockIdx.y * 128;
  const int o_base = MODE ? n0 : m0;
  const int s_base = MODE ? m0 : n0;
  const int t = threadIdx.x;
  const int w = t >> 6, lane = t & 63, lr = lane & 15, lq = lane >> 4;
  const int wm = (w >> 1) * 64, wn = (w & 1) * 64;

  f32x4 acc[4][4] = {};

  for (int kt = 0; kt < 16; ++kt) {
    const int c0 = kt * 32;
    __syncthreads();
#pragma unroll
    for (int p = 0; p < 4; ++p) {
      const int idx = p * 256 + t;
      const int row = idx >> 3, cq = (idx & 7) * 4;
      const float4 v = *(const float4*)&Wg[(size_t)(o_base + row) * DA + c0 + cq];
      h4_t hv;
      hv[0] = (f16)v.x; hv[1] = (f16)v.y; hv[2] = (f16)v.z; hv[3] = (f16)v.w;
      *(h4_t*)&Wl[row * 40 + cq] = hv;
    }
#pragma unroll
    for (int p = 0; p < 4; ++p) {
      const int idx = p * 256 + t;
      const int cc = idx >> 5, s4 = (idx & 31) * 4;
      const float4 v = *(const float4*)&Xin[((size_t)b * DA + c0 + cc) * SL + s_base + s4];
      *(float4*)&Xf32[cc * 132 + s4] = v;
    }
    __syncthreads();
    {
      const int srow = t >> 1, cb = (t & 1) * 16;
      h8_t lo, hi;
#pragma unroll
      for (int u = 0; u < 8; ++u) lo[u] = (f16)Xf32[(cb + u) * 132 + srow];
#pragma unroll
      for (int u = 0; u < 8; ++u) hi[u] = (f16)Xf32[(cb + 8 + u) * 132 + srow];
      *(h8_t*)&Xl[srow * 40 + cb] = lo;
      *(h8_t*)&Xl[srow * 40 + cb + 8] = hi;
    }
    __syncthreads();
    const f16* Alp = MODE ? Xl : Wl;
    const f16* Blp = MODE ? Wl : Xl;
    h8_t af[4], bf[4];
#pragma unroll
    for (int i = 0; i < 4; ++i) af[i] = *(const h8_t*)&Alp[(wm + i * 16 + lr) * 40 + lq * 8];
#pragma unroll
    for (int j = 0; j < 4; ++j) bf[j] = *(const h8_t*)&Blp[(wn + j * 16 + lr) * 40 + lq * 8];
#pragma unroll
    for (int i = 0; i < 4; ++i)
#pragma unroll
      for (int j = 0; j < 4; ++j)
        acc[i][j] = __builtin_amdgcn_mfma_f32_16x16x32_f16(af[i], bf[j], acc[i][j], 0, 0, 0);
  }

#pragma unroll
  for (int i = 0; i < 4; ++i) {
    const int gmb = m0 + wm + i * 16 + lq * 4;
    float bm[4] = {0.f, 0.f, 0.f, 0.f};
    if (MODE == 0) {
      const float4 b4 = *(const float4*)&bias[gmb];
      bm[0] = b4.x; bm[1] = b4.y; bm[2] = b4.z; bm[3] = b4.w;
    }
#pragma unroll
    for (int j = 0; j < 4; ++j) {
      const int gn = n0 + wn + j * 16 + lr;
      const float bn = (MODE == 1) ? bias[gn] : 0.f;
      h4_t hv;
#pragma unroll
      for (int r = 0; r < 4; ++r) {
        const float val = acc[i][j][r] + (MODE == 0 ? bm[r] : bn);
        hv[r] = (f16)val;
      }
      *(h4_t*)&outg[((size_t)b * NT + gn) * MT + gmb] = hv;
    }
  }
}

// ---------------------------------------------------------------------------
// K2: fused flash attention. i-tile back to 256 (grid (BS*NH, SL/256) = 512
// blocks, 2/CU) -- halves KV re-fetch vs R2. Mask converted ONCE to additive
// f32 bias (0 / -1e9) in LDS: per-tile reads are broadcast ds_read_b128
// (lgkm), so NO global load sits between the K/V prefetch issue and its LDS
// write -> prefetch stays in flight across the whole tile body.
// Keeps: sigma-permuted K (P regs->PV), tree-max, defer-max (T13),
// 4-acc exp2 sum, setprio (T5) around MFMA clusters.
// ---------------------------------------------------------------------------
__global__ __launch_bounds__(256, 2) void attn_kernel(
    const float* __restrict__ qg, const f16* __restrict__ kp, const f16* __restrict__ vp,
    const float* __restrict__ gamma, const float* __restrict__ gbns,
    const int* __restrict__ maskg, float* __restrict__ outg) {
  __shared__ __align__(16) char smem[36864 + 4096];
  f16* KV = (f16*)smem;       // 2 bufs x (K[64][72] + V[64][72]) f16
  float* Osh = (float*)smem;  // epilogue overlay [32 d][256 i] f32
  float* biasf = (float*)(smem + 36864);  // [SL] additive key-mask bias

  const int bh = blockIdx.x, b = bh >> 3, h = bh & 7;
  const int i0 = blockIdx.y * 256;
  const int t = threadIdx.x, w = t >> 6, lane = t & 63;
  const int l5 = lane & 31, hf = lane >> 5;
  const float scale = gamma[h] / gbns[h] * 1.44269504088896f;  // GBN scale * log2(e)

  // ---- Q fragments straight from global (B-operand: n=i, k=d)
  h8_t qf[2][4];
#pragma unroll
  for (int im = 0; im < 2; ++im)
#pragma unroll
    for (int ks = 0; ks < 4; ++ks) {
      h8_t v;
#pragma unroll
      for (int u = 0; u < 8; ++u) {
        const int d = ks * 16 + hf * 8 + u;
        v[u] = (f16)(qg[((size_t)b * DA + h * DH + d) * SL + i0 + w * 64 + im * 32 + l5] * scale);
      }
      qf[im][ks] = v;
    }

  // ---- mask -> additive bias, staged to LDS once
  {
    const int4 m4 = *(const int4*)&maskg[b * SL + t * 4];
    float4 b4;
    b4.x = m4.x ? -1e9f : 0.f;
    b4.y = m4.y ? -1e9f : 0.f;
    b4.z = m4.z ? -1e9f : 0.f;
    b4.w = m4.w ? -1e9f : 0.f;
    *(float4*)&biasf[t * 4] = b4;
  }

  const int srow = t >> 3;        // 0..31 (p adds 32)
  const int c8 = (t & 7) * 8;

  // ---- stage tile 0 (K rows sigma-permuted: swap bits 2,3)
  uint4 rk[2], rv[2];
#pragma unroll
  for (int p = 0; p < 2; ++p) {
    const int row = p * 32 + srow;
    rk[p] = *(const uint4*)&kp[((size_t)b * SL + row) * DA + h * DH + c8];
    rv[p] = *(const uint4*)&vp[((size_t)b * DA + h * DH + row) * SL + c8];
  }
  {
    f16* K0 = KV;
    f16* V0 = KV + 4608;
#pragma unroll
    for (int p = 0; p < 2; ++p) {
      const int row = p * 32 + srow;
      const int rowp = (row & ~12) | ((row & 4) << 1) | ((row & 8) >> 1);
      *(uint4*)&K0[rowp * 72 + c8] = rk[p];
      *(uint4*)&V0[row * 72 + c8] = rv[p];
    }
  }
  __syncthreads();  // KV tile 0 + bias table ready

  float m_i[2] = {-3e38f, -3e38f}, l_i[2] = {0.f, 0.f};
  f32x16 acc[2][2] = {};  // [im][nd]: rows d = nd*32 + r(e,hf), col i = lane

  for (int jt = 0; jt < 16; ++jt) {
    const int j0 = jt * 64;
    const f16* Kc = KV + (jt & 1) * 9216;
    const f16* Vc = Kc + 4608;

    // prefetch next tile into regs (written at loop bottom; nothing below
    // forces a vmcnt drain before that write)
    if (jt < 15) {
      const int jn = j0 + 64;
#pragma unroll
      for (int p = 0; p < 2; ++p) {
        const int row = p * 32 + srow;
        rk[p] = *(const uint4*)&kp[((size_t)b * SL + jn + row) * DA + h * DH + c8];
        rv[p] = *(const uint4*)&vp[((size_t)b * DA + h * DH + row) * SL + jn + c8];
      }
    }

    // S^T = K * Q^T : rows = permuted K rows, cols = i
    f32x16 sa[2][2] = {};
    __builtin_amdgcn_s_setprio(1);
#pragma unroll
    for (int ks = 0; ks < 4; ++ks)
#pragma unroll
      for (int mj = 0; mj < 2; ++mj) {
        const h8_t kf = *(const h8_t*)&Kc[(mj * 32 + l5) * 72 + ks * 16 + hf * 8];
#pragma unroll
        for (int im = 0; im < 2; ++im)
          sa[im][mj] = __builtin_amdgcn_mfma_f32_32x32x16_f16(kf, qf[im][ks], sa[im][mj], 0, 0, 0);
      }
    __builtin_amdgcn_s_setprio(0);

    // key-mask bias add (broadcast LDS reads; sigma-mapped j)
#pragma unroll
    for (int mj = 0; mj < 2; ++mj)
#pragma unroll
      for (int qq = 0; qq < 4; ++qq) {
        const float4 bq = *(const float4*)&biasf[j0 + mj * 32 + (qq >> 1) * 16 + hf * 8 + (qq & 1) * 4];
#pragma unroll
        for (int im = 0; im < 2; ++im) {
          sa[im][mj][qq * 4 + 0] += bq.x;
          sa[im][mj][qq * 4 + 1] += bq.y;
          sa[im][mj][qq * 4 + 2] += bq.z;
          sa[im][mj][qq * 4 + 3] += bq.w;
        }
      }

    // ---- online softmax: tree max, defer-max, 4-acc exp2 sums
#pragma unroll
    for (int im = 0; im < 2; ++im) {
      float a[8];
#pragma unroll
      for (int u = 0; u < 8; ++u)
        a[u] = fmaxf(fmaxf(sa[im][0][u], sa[im][0][u + 8]),
                     fmaxf(sa[im][1][u], sa[im][1][u + 8]));
      float mx = fmaxf(fmaxf(fmaxf(a[0], a[1]), fmaxf(a[2], a[3])),
                       fmaxf(fmaxf(a[4], a[5]), fmaxf(a[6], a[7])));
      mx = fmaxf(mx, __shfl_xor(mx, 32));
      if (!__all(mx - m_i[im] <= 8.0f)) {  // T13: skip rescale when bounded
        const float mn = fmaxf(m_i[im], mx);
        const float alpha = __builtin_amdgcn_exp2f(m_i[im] - mn);
        m_i[im] = mn;
        l_i[im] *= alpha;
#pragma unroll
        for (int nd = 0; nd < 2; ++nd)
#pragma unroll
          for (int e = 0; e < 16; ++e) acc[im][nd][e] *= alpha;
      }
      float r0 = 0.f, r1 = 0.f, r2 = 0.f, r3 = 0.f;
#pragma unroll
      for (int mj = 0; mj < 2; ++mj)
#pragma unroll
        for (int e = 0; e < 16; e += 4) {
          const float p0 = __builtin_amdgcn_exp2f(sa[im][mj][e + 0] - m_i[im]);
          const float p1 = __builtin_amdgcn_exp2f(sa[im][mj][e + 1] - m_i[im]);
          const float p2 = __builtin_amdgcn_exp2f(sa[im][mj][e + 2] - m_i[im]);
          const float p3 = __builtin_amdgcn_exp2f(sa[im][mj][e + 3] - m_i[im]);
          sa[im][mj][e + 0] = p0; sa[im][mj][e + 1] = p1;
          sa[im][mj][e + 2] = p2; sa[im][mj][e + 3] = p3;
          r0 += p0; r1 += p1; r2 += p2; r3 += p3;
        }
      float rs = (r0 + r1) + (r2 + r3);
      rs += __shfl_xor(rs, 32);
      l_i[im] += rs;
    }

    // O^T += V^T * P^T : A = V^T[d][j] from LDS, B = P^T straight from regs
    __builtin_amdgcn_s_setprio(1);
#pragma unroll
    for (int jk = 0; jk < 4; ++jk) {
      const int mj = jk >> 1, g = jk & 1;
      h8_t pf[2];
#pragma unroll
      for (int im = 0; im < 2; ++im) {
        h8_t pk;
#pragma unroll
        for (int u = 0; u < 8; ++u) pk[u] = (f16)sa[im][mj][g * 8 + u];
        pf[im] = pk;
      }
#pragma unroll
      for (int nd = 0; nd < 2; ++nd) {
        const h8_t vf = *(const h8_t*)&Vc[(nd * 32 + l5) * 72 + jk * 16 + hf * 8];
#pragma unroll
        for (int im = 0; im < 2; ++im)
          acc[im][nd] = __builtin_amdgcn_mfma_f32_32x32x16_f16(vf, pf[im], acc[im][nd], 0, 0, 0);
      }
    }
    __builtin_amdgcn_s_setprio(0);

    // write prefetched tile into the other buffer; ONE barrier per tile
    if (jt < 15) {
      f16* Kn = KV + ((jt + 1) & 1) * 9216;
      f16* Vn = Kn + 4608;
#pragma unroll
      for (int p = 0; p < 2; ++p) {
        const int row = p * 32 + srow;
        const int rowp = (row & ~12) | ((row & 4) << 1) | ((row & 8) >> 1);
        *(uint4*)&Kn[rowp * 72 + c8] = rk[p];
        *(uint4*)&Vn[row * 72 + c8] = rv[p];
      }
      __syncthreads();
    }
  }

  // ---- epilogue: per-lane 1/l (0 for masked query rows), LDS bounce per nd
  float fac[2];
#pragma unroll
  for (int im = 0; im < 2; ++im) {
    const int mo = maskg[b * SL + i0 + w * 64 + im * 32 + l5];
    fac[im] = mo ? 0.f : 1.f / l_i[im];
  }
  __syncthreads();  // all waves done reading KV before Osh overlay

#pragma unroll
  for (int nd = 0; nd < 2; ++nd) {
    // scatter acc into Osh [d_local][i_block] (2-way conflicts only)
#pragma unroll
    for (int im = 0; im < 2; ++im)
#pragma unroll
      for (int e = 0; e < 16; ++e) {
        const int dl = (e & 3) + 8 * (e >> 2) + 4 * hf;
        Osh[dl * 256 + w * 64 + im * 32 + l5] = acc[im][nd][e] * fac[im];
      }
    __syncthreads();
    // coalesced store: 1KB contiguous per d-row
#pragma unroll
    for (int pass = 0; pass < 8; ++pass) {
      const int row = pass * 4 + w;
      const int i4 = lane * 4;
      const float4 o = *(const float4*)&Osh[row * 256 + i4];
      *(float4*)&outg[((size_t)b * DA + h * DH + nd * 32 + row) * SL + i0 + i4] = o;
    }
    __syncthreads();  // before next nd pass overwrites Osh
  }
}

// ---------------------------------------------------------------------------
extern "C" void kernel_launch(void* const* d_in, const int* in_sizes, int n_in,
                              void* d_out, int out_size, void* d_ws, size_t ws_size,
                              hipStream_t stream) {
  const float* q     = (const float*)d_in[0];
  const float* k_in  = (const float*)d_in[1];
  const float* v_in  = (const float*)d_in[2];
  const float* k_w   = (const float*)d_in[3];
  const float* k_b   = (const float*)d_in[4];
  const float* v_w   = (const float*)d_in[5];
  const float* v_b   = (const float*)d_in[6];
  const float* gamma = (const float*)d_in[7];
  const float* gbns  = (const float*)d_in[10];  // gbn_bias/gbn_m cancel under softmax
  const int*   mask  = (const int*)d_in[11];
  float* out = (float*)d_out;

  const size_t NEL = (size_t)BS * SL * DA;
  f16* kpw = (f16*)d_ws;        // k projection, [b][s][o], 16 MiB
  f16* vpw = kpw + NEL;         // v projection, [b][o][s], 16 MiB

  const size_t need = NEL * 2 * 4 + (size_t)DA * DA * 2 * 2;  // 64 MiB + 1 MiB
  if (ws_size >= need) {
    f16* Kt  = vpw + NEL;       // k_in transposed+converted, [b][s][c], 16 MiB
    f16* Vt  = Kt + NEL;        // v_in transposed+converted, [b][s][c], 16 MiB
    f16* kwh = Vt + NEL;        // k_w f16, [o][c]
    f16* vwh = kwh + (size_t)DA * DA;
    prep_kernel<<<dim3(2112), 256, 0, stream>>>(k_in, v_in, k_w, v_w, Kt, Vt, kwh, vwh);
    proj_gemm_all<<<dim3(32, BS, 2), 256, 0, stream>>>(kwh, vwh, Kt, Vt, k_b, v_b, kpw, vpw);
  } else {
    // fallback: old fused path (32 MiB workspace)
    fused_proj<0><<<dim3(4, 8, BS), 256, 0, stream>>>(k_w, k_in, k_b, kpw);
    fused_proj<1><<<dim3(8, 4, BS), 256, 0, stream>>>(v_w, v_in, v_b, vpw);
  }
  attn_kernel<<<dim3(BS * NH, SL / 256), 256, 0, stream>>>(q, kpw, vpw, gamma, gbns, mask, out);
}

// Round 5
// 236.723 us; speedup vs baseline: 1.6505x; 1.6505x over previous
//
#include <hip/hip_runtime.h>

typedef _Float16 f16;
typedef _Float16 h8_t __attribute__((ext_vector_type(8)));
typedef _Float16 h4_t __attribute__((ext_vector_type(4)));
typedef float f32x4 __attribute__((ext_vector_type(4)));
typedef float f32x16 __attribute__((ext_vector_type(16)));

#define BS 16
#define DA 512
#define SL 1024
#define NH 8
#define DH 64

// direct global->LDS DMA, 16B per lane. HW dest = wave-uniform base + lane*16,
// so lane i's lds pointer must equal base + i*16 (linear layout).
__device__ __forceinline__ void gload_lds16(const void* g, void* l) {
  __builtin_amdgcn_global_load_lds((const __attribute__((address_space(1))) void*)g,
                                   (__attribute__((address_space(3))) void*)l, 16, 0, 0);
}

// ---------------------------------------------------------------------------
// P0: prep pass (unchanged).
//  blocks [0,2048):   transpose+convert X [b][c][s] f32 -> Xt [b][s][c] f16
//  blocks [2048,2112): convert k_w / v_w f32 -> f16
// ---------------------------------------------------------------------------
__global__ __launch_bounds__(256) void prep_kernel(
    const float* __restrict__ k_in, const float* __restrict__ v_in,
    const float* __restrict__ k_w, const float* __restrict__ v_w,
    f16* __restrict__ Kt, f16* __restrict__ Vt,
    f16* __restrict__ kwh, f16* __restrict__ vwh) {
  const int blk = blockIdx.x;
  const int t = threadIdx.x;
  if (blk < 2048) {
    const int which = blk >> 10;        // 0: k_in, 1: v_in
    const int r = blk & 1023;
    const int b = r >> 6;               // 0..15
    const int c0 = ((r >> 3) & 7) * 64; // 8 c-tiles
    const int s0 = (r & 7) * 128;       // 8 s-tiles
    const float* src = which ? v_in : k_in;
    f16* dst = which ? Vt : Kt;
    __shared__ __align__(16) float Xf32[64 * 132];
#pragma unroll
    for (int p = 0; p < 8; ++p) {
      const int idx = p * 256 + t;
      const int cc = idx >> 5, s4 = (idx & 31) * 4;
      const float4 v = *(const float4*)&src[((size_t)b * DA + c0 + cc) * SL + s0 + s4];
      *(float4*)&Xf32[cc * 132 + s4] = v;
    }
    __syncthreads();
    const int srow = t >> 1, cb = (t & 1) * 32;
#pragma unroll
    for (int g = 0; g < 4; ++g) {
      h8_t h;
#pragma unroll
      for (int u = 0; u < 8; ++u) h[u] = (f16)Xf32[(cb + g * 8 + u) * 132 + srow];
      *(h8_t*)&dst[((size_t)b * SL + s0 + srow) * DA + c0 + cb + g * 8] = h;
    }
  } else {
    const int r = blk - 2048;           // 0..63
    const int wsel = r >> 5;            // 0: k_w, 1: v_w
    const float* src = wsel ? v_w : k_w;
    f16* dst = wsel ? vwh : kwh;
    const int base = (r & 31) * 8192;
#pragma unroll
    for (int p = 0; p < 4; ++p) {
      const int i = base + p * 2048 + t * 8;
      const float4 a = *(const float4*)&src[i];
      const float4 c = *(const float4*)&src[i + 4];
      h8_t h;
      h[0] = (f16)a.x; h[1] = (f16)a.y; h[2] = (f16)a.z; h[3] = (f16)a.w;
      h[4] = (f16)c.x; h[5] = (f16)c.y; h[6] = (f16)c.z; h[7] = (f16)c.w;
      *(h8_t*)&dst[i] = h;
    }
  }
}

// ---------------------------------------------------------------------------
// K1: merged projection GEMM, 2-phase pipelined (R2-verified structure).
//   stage tile kt+1 at TOP of iter kt -> ds_read+MFMA of tile kt overlaps the
//   global->LDS latency -> single barrier (vmcnt drain) at bottom.
// grid (32 tiles, BS, 2 modes) = 1024 blocks = 4 blocks/CU (LDS 32KB dbuf).
// mode 0 (k-proj): A = kwh [o][c],    B = Kt[b] [s][c], out kp[b][s][o] + k_b(m)
// mode 1 (v-proj): A = Vt[b] [s][c],  B = vwh [o][c],   out vp[b][o][s] + v_b(n)
// ---------------------------------------------------------------------------
__global__ __launch_bounds__(256, 4) void proj_gemm_all(
    const f16* __restrict__ kwh, const f16* __restrict__ vwh,
    const f16* __restrict__ Kt, const f16* __restrict__ Vt,
    const float* __restrict__ k_b, const float* __restrict__ v_b,
    f16* __restrict__ kp, f16* __restrict__ vp) {
  __shared__ __align__(16) f16 LD[2][8192];  // [buf][Al 4096 | Bl 4096] f16
  const int mode = blockIdx.z;
  const int b = blockIdx.y;
  const int tx = blockIdx.x;                  // 32 tiles per (b, mode)
  const int m0 = (mode ? (tx >> 2) : (tx & 3)) * 128;
  const int n0 = (mode ? (tx & 3) : (tx >> 2)) * 128;
  const int t = threadIdx.x;
  const int lane = t & 63, w = t >> 6, lr = lane & 15, lq = lane >> 4;
  const int wm = (w >> 1) * 64, wn = (w & 1) * 64;

  const f16* Arow = (mode ? Vt + (size_t)b * SL * DA : kwh) + (size_t)m0 * DA;
  const f16* Brow = (mode ? vwh : Kt + (size_t)b * SL * DA) + (size_t)n0 * DA;

  const int rr = t >> 2;          // 0..63: tile row (lower half)
  const int c8 = (t & 3) * 8;     // f16 col within the 32-wide K-slice
  const int lo8 = t * 8;          // LDS f16 offset (linear: lane*16B)

  const f16* ga0 = Arow + (size_t)rr * DA + c8;
  const f16* ga1 = Arow + (size_t)(64 + rr) * DA + c8;
  const f16* gb0 = Brow + (size_t)rr * DA + c8;
  const f16* gb1 = Brow + (size_t)(64 + rr) * DA + c8;

  f32x4 acc[4][4] = {};

  // prologue: stage tile 0 into buf 0
  gload_lds16(ga0, &LD[0][0] + lo8);
  gload_lds16(ga1, &LD[0][2048] + lo8);
  gload_lds16(gb0, &LD[0][4096] + lo8);
  gload_lds16(gb1, &LD[0][6144] + lo8);
  ga0 += 32; ga1 += 32; gb0 += 32; gb1 += 32;
  __syncthreads();  // drains vmcnt(0): tile 0 resident

  for (int kt = 0; kt < 16; ++kt) {
    const int cur = kt & 1;
    if (kt < 15) {  // issue next-tile loads FIRST; they stay in flight
      f16* nb = &LD[cur ^ 1][0];
      gload_lds16(ga0, nb + lo8);
      gload_lds16(ga1, nb + 2048 + lo8);
      gload_lds16(gb0, nb + 4096 + lo8);
      gload_lds16(gb1, nb + 6144 + lo8);
      ga0 += 32; ga1 += 32; gb0 += 32; gb1 += 32;
    }
    const f16* Al = &LD[cur][0];
    const f16* Bl = &LD[cur][4096];
    h8_t af[4], bf[4];
#pragma unroll
    for (int i = 0; i < 4; ++i) af[i] = *(const h8_t*)&Al[(wm + i * 16 + lr) * 32 + lq * 8];
#pragma unroll
    for (int j = 0; j < 4; ++j) bf[j] = *(const h8_t*)&Bl[(wn + j * 16 + lr) * 32 + lq * 8];
    __builtin_amdgcn_s_setprio(1);
#pragma unroll
    for (int i = 0; i < 4; ++i)
#pragma unroll
      for (int j = 0; j < 4; ++j)
        acc[i][j] = __builtin_amdgcn_mfma_f32_16x16x32_f16(af[i], bf[j], acc[i][j], 0, 0, 0);
    __builtin_amdgcn_s_setprio(0);
    __syncthreads();  // one drain per tile: next tile resident, cur readable
  }

  // epilogue: D row = gm (4 consecutive per lane -> 8B f16 stores), col = gn
#pragma unroll
  for (int i = 0; i < 4; ++i) {
    const int gmb = m0 + wm + i * 16 + lq * 4;
    float bm[4] = {0.f, 0.f, 0.f, 0.f};
    if (mode == 0) {
      const float4 b4 = *(const float4*)&k_b[gmb];
      bm[0] = b4.x; bm[1] = b4.y; bm[2] = b4.z; bm[3] = b4.w;
    }
#pragma unroll
    for (int j = 0; j < 4; ++j) {
      const int gn = n0 + wn + j * 16 + lr;
      const float bn = mode ? v_b[gn] : 0.f;
      h4_t hv;
#pragma unroll
      for (int r = 0; r < 4; ++r) {
        const float val = acc[i][j][r] + (mode == 0 ? bm[r] : bn);
        hv[r] = (f16)val;
      }
      f16* dst = mode ? &vp[((size_t)b * DA + gn) * SL + gmb]
                      : &kp[((size_t)b * SL + gn) * DA + gmb];
      *(h4_t*)dst = hv;
    }
  }
}

// ---------------------------------------------------------------------------
// Fallback: fused transpose+projection kernel (small-workspace path only).
// ---------------------------------------------------------------------------
template <int MODE>
__global__ __launch_bounds__(256) void fused_proj(const float* __restrict__ Wg,
                                                  const float* __restrict__ Xin,
                                                  const float* __restrict__ bias,
                                                  f16* __restrict__ outg) {
  constexpr int MT = MODE ? SL : DA;
  constexpr int NT = MODE ? DA : SL;
  __shared__ f16 Wl[128 * 40];
  __shared__ f16 Xl[128 * 40];
  __shared__ float Xf32[32 * 132];
  const int b = blockIdx.z;
  const int m0 = blockIdx.x * 128;
  const int n0 = blockIdx.y * 128;
  const int o_base = MODE ? n0 : m0;
  const int s_base = MODE ? m0 : n0;
  const int t = threadIdx.x;
  const int w = t >> 6, lane = t & 63, lr = lane & 15, lq = lane >> 4;
  const int wm = (w >> 1) * 64, wn = (w & 1) * 64;

  f32x4 acc[4][4] = {};

  for (int kt = 0; kt < 16; ++kt) {
    const int c0 = kt * 32;
    __syncthreads();
#pragma unroll
    for (int p = 0; p < 4; ++p) {
      const int idx = p * 256 + t;
      const int row = idx >> 3, cq = (idx & 7) * 4;
      const float4 v = *(const float4*)&Wg[(size_t)(o_base + row) * DA + c0 + cq];
      h4_t hv;
      hv[0] = (f16)v.x; hv[1] = (f16)v.y; hv[2] = (f16)v.z; hv[3] = (f16)v.w;
      *(h4_t*)&Wl[row * 40 + cq] = hv;
    }
#pragma unroll
    for (int p = 0; p < 4; ++p) {
      const int idx = p * 256 + t;
      const int cc = idx >> 5, s4 = (idx & 31) * 4;
      const float4 v = *(const float4*)&Xin[((size_t)b * DA + c0 + cc) * SL + s_base + s4];
      *(float4*)&Xf32[cc * 132 + s4] = v;
    }
    __syncthreads();
    {
      const int srow = t >> 1, cb = (t & 1) * 16;
      h8_t lo, hi;
#pragma unroll
      for (int u = 0; u < 8; ++u) lo[u] = (f16)Xf32[(cb + u) * 132 + srow];
#pragma unroll
      for (int u = 0; u < 8; ++u) hi[u] = (f16)Xf32[(cb + 8 + u) * 132 + srow];
      *(h8_t*)&Xl[srow * 40 + cb] = lo;
      *(h8_t*)&Xl[srow * 40 + cb + 8] = hi;
    }
    __syncthreads();
    const f16* Alp = MODE ? Xl : Wl;
    const f16* Blp = MODE ? Wl : Xl;
    h8_t af[4], bf[4];
#pragma unroll
    for (int i = 0; i < 4; ++i) af[i] = *(const h8_t*)&Alp[(wm + i * 16 + lr) * 40 + lq * 8];
#pragma unroll
    for (int j = 0; j < 4; ++j) bf[j] = *(const h8_t*)&Blp[(wn + j * 16 + lr) * 40 + lq * 8];
#pragma unroll
    for (int i = 0; i < 4; ++i)
#pragma unroll
      for (int j = 0; j < 4; ++j)
        acc[i][j] = __builtin_amdgcn_mfma_f32_16x16x32_f16(af[i], bf[j], acc[i][j], 0, 0, 0);
  }

#pragma unroll
  for (int i = 0; i < 4; ++i) {
    const int gmb = m0 + wm + i * 16 + lq * 4;
    float bm[4] = {0.f, 0.f, 0.f, 0.f};
    if (MODE == 0) {
      const float4 b4 = *(const float4*)&bias[gmb];
      bm[0] = b4.x; bm[1] = b4.y; bm[2] = b4.z; bm[3] = b4.w;
    }
#pragma unroll
    for (int j = 0; j < 4; ++j) {
      const int gn = n0 + wn + j * 16 + lr;
      const float bn = (MODE == 1) ? bias[gn] : 0.f;
      h4_t hv;
#pragma unroll
      for (int r = 0; r < 4; ++r) {
        const float val = acc[i][j][r] + (MODE == 0 ? bm[r] : bn);
        hv[r] = (f16)val;
      }
      *(h4_t*)&outg[((size_t)b * NT + gn) * MT + gmb] = hv;
    }
  }
}

// ---------------------------------------------------------------------------
// K2: fused flash attention, 8-WAVE blocks (512 threads): i-tile stays 256
// (512 blocks, same KV traffic as R0) but each wave owns 32 queries ->
// 16 waves/CU = 4 waves/SIMD (was 2). The QK->softmax->PV phase convoy now
// overlaps across 4 staggered waves per SIMD: softmax (VALU) of one wave
// hides under MFMA of others. Per-wave state halved (VGPR ~90, cap 128).
// Mask is additive f32 bias in LDS (no global load between KV prefetch issue
// and consume). Keeps: sigma-permuted K (P regs->PV), tree-max, defer-max,
// 4-acc exp2 sum, setprio.
// ---------------------------------------------------------------------------
__global__ __launch_bounds__(512, 4) void attn_kernel(
    const float* __restrict__ qg, const f16* __restrict__ kp, const f16* __restrict__ vp,
    const float* __restrict__ gamma, const float* __restrict__ gbns,
    const int* __restrict__ maskg, float* __restrict__ outg) {
  __shared__ __align__(16) char smem[36864 + 4096];
  f16* KV = (f16*)smem;       // 2 bufs x (K[64][72] + V[64][72]) f16
  float* Osh = (float*)smem;  // epilogue overlay [32 d][256 i] f32
  float* biasf = (float*)(smem + 36864);  // [SL] additive key-mask bias

  const int bh = blockIdx.x, b = bh >> 3, h = bh & 7;
  const int i0 = blockIdx.y * 256;
  const int t = threadIdx.x, w = t >> 6, lane = t & 63;
  const int l5 = lane & 31, hf = lane >> 5;
  const float scale = gamma[h] / gbns[h] * 1.44269504088896f;  // GBN scale * log2(e)
  const int iw = i0 + w * 32 + l5;  // this lane's query column

  // ---- Q fragments straight from global (B-operand: n=i, k=d)
  h8_t qf[4];
#pragma unroll
  for (int ks = 0; ks < 4; ++ks) {
    h8_t v;
#pragma unroll
    for (int u = 0; u < 8; ++u) {
      const int d = ks * 16 + hf * 8 + u;
      v[u] = (f16)(qg[((size_t)b * DA + h * DH + d) * SL + iw] * scale);
    }
    qf[ks] = v;
  }

  // ---- mask -> additive bias, staged to LDS once (512 threads x 2)
  {
    const int2 m2 = *(const int2*)&maskg[b * SL + t * 2];
    biasf[t * 2 + 0] = m2.x ? -1e9f : 0.f;
    biasf[t * 2 + 1] = m2.y ? -1e9f : 0.f;
  }

  const int srow = t >> 3;        // 0..63 with 512 threads
  const int c8 = (t & 7) * 8;

  // ---- stage tile 0 (K rows sigma-permuted: swap bits 2,3); 1 uint4/thread
  uint4 rk = *(const uint4*)&kp[((size_t)b * SL + srow) * DA + h * DH + c8];
  uint4 rv = *(const uint4*)&vp[((size_t)b * DA + h * DH + srow) * SL + c8];
  {
    f16* K0 = KV;
    f16* V0 = KV + 4608;
    const int rowp = (srow & ~12) | ((srow & 4) << 1) | ((srow & 8) >> 1);
    *(uint4*)&K0[rowp * 72 + c8] = rk;
    *(uint4*)&V0[srow * 72 + c8] = rv;
  }
  __syncthreads();  // KV tile 0 + bias table ready

  float m_i = -3e38f, l_i = 0.f;
  f32x16 acc[2] = {};  // [nd]: rows d = nd*32 + r(e,hf), col i = l5

  for (int jt = 0; jt < 16; ++jt) {
    const int j0 = jt * 64;
    const f16* Kc = KV + (jt & 1) * 9216;
    const f16* Vc = Kc + 4608;

    // prefetch next tile into regs (written at loop bottom; nothing below
    // forces a vmcnt drain before that write)
    if (jt < 15) {
      const int jn = j0 + 64;
      rk = *(const uint4*)&kp[((size_t)b * SL + jn + srow) * DA + h * DH + c8];
      rv = *(const uint4*)&vp[((size_t)b * DA + h * DH + srow) * SL + jn + c8];
    }

    // S^T = K * Q^T : rows = permuted K rows, cols = i
    f32x16 sa[2] = {};
    __builtin_amdgcn_s_setprio(1);
#pragma unroll
    for (int ks = 0; ks < 4; ++ks)
#pragma unroll
      for (int mj = 0; mj < 2; ++mj) {
        const h8_t kf = *(const h8_t*)&Kc[(mj * 32 + l5) * 72 + ks * 16 + hf * 8];
        sa[mj] = __builtin_amdgcn_mfma_f32_32x32x16_f16(kf, qf[ks], sa[mj], 0, 0, 0);
      }
    __builtin_amdgcn_s_setprio(0);

    // key-mask bias add (broadcast LDS reads; sigma-mapped j)
#pragma unroll
    for (int mj = 0; mj < 2; ++mj)
#pragma unroll
      for (int qq = 0; qq < 4; ++qq) {
        const float4 bq = *(const float4*)&biasf[j0 + mj * 32 + (qq >> 1) * 16 + hf * 8 + (qq & 1) * 4];
        sa[mj][qq * 4 + 0] += bq.x;
        sa[mj][qq * 4 + 1] += bq.y;
        sa[mj][qq * 4 + 2] += bq.z;
        sa[mj][qq * 4 + 3] += bq.w;
      }

    // ---- online softmax: tree max, defer-max (T13), 4-acc exp2 sums
    {
      float a[8];
#pragma unroll
      for (int u = 0; u < 8; ++u)
        a[u] = fmaxf(fmaxf(sa[0][u], sa[0][u + 8]), fmaxf(sa[1][u], sa[1][u + 8]));
      float mx = fmaxf(fmaxf(fmaxf(a[0], a[1]), fmaxf(a[2], a[3])),
                       fmaxf(fmaxf(a[4], a[5]), fmaxf(a[6], a[7])));
      mx = fmaxf(mx, __shfl_xor(mx, 32));
      if (!__all(mx - m_i <= 8.0f)) {  // skip rescale while tile max bounded
        const float mn = fmaxf(m_i, mx);
        const float alpha = __builtin_amdgcn_exp2f(m_i - mn);
        m_i = mn;
        l_i *= alpha;
#pragma unroll
        for (int nd = 0; nd < 2; ++nd)
#pragma unroll
          for (int e = 0; e < 16; ++e) acc[nd][e] *= alpha;
      }
      float r0 = 0.f, r1 = 0.f, r2 = 0.f, r3 = 0.f;
#pragma unroll
      for (int mj = 0; mj < 2; ++mj)
#pragma unroll
        for (int e = 0; e < 16; e += 4) {
          const float p0 = __builtin_amdgcn_exp2f(sa[mj][e + 0] - m_i);
          const float p1 = __builtin_amdgcn_exp2f(sa[mj][e + 1] - m_i);
          const float p2 = __builtin_amdgcn_exp2f(sa[mj][e + 2] - m_i);
          const float p3 = __builtin_amdgcn_exp2f(sa[mj][e + 3] - m_i);
          sa[mj][e + 0] = p0; sa[mj][e + 1] = p1;
          sa[mj][e + 2] = p2; sa[mj][e + 3] = p3;
          r0 += p0; r1 += p1; r2 += p2; r3 += p3;
        }
      float rs = (r0 + r1) + (r2 + r3);
      rs += __shfl_xor(rs, 32);
      l_i += rs;
    }

    // O^T += V^T * P^T : A = V^T[d][j] from LDS, B = P^T straight from regs
    // (sigma cancellation: B slot k holds logical j = k)
    __builtin_amdgcn_s_setprio(1);
#pragma unroll
    for (int jk = 0; jk < 4; ++jk) {
      const int mj = jk >> 1, g = jk & 1;
      h8_t pk;
#pragma unroll
      for (int u = 0; u < 8; ++u) pk[u] = (f16)sa[mj][g * 8 + u];
#pragma unroll
      for (int nd = 0; nd < 2; ++nd) {
        const h8_t vf = *(const h8_t*)&Vc[(nd * 32 + l5) * 72 + jk * 16 + hf * 8];
        acc[nd] = __builtin_amdgcn_mfma_f32_32x32x16_f16(vf, pk, acc[nd], 0, 0, 0);
      }
    }
    __builtin_amdgcn_s_setprio(0);

    // write prefetched tile into the other buffer; ONE barrier per tile
    if (jt < 15) {
      f16* Kn = KV + ((jt + 1) & 1) * 9216;
      f16* Vn = Kn + 4608;
      const int rowp = (srow & ~12) | ((srow & 4) << 1) | ((srow & 8) >> 1);
      *(uint4*)&Kn[rowp * 72 + c8] = rk;
      *(uint4*)&Vn[srow * 72 + c8] = rv;
      __syncthreads();
    }
  }

  // ---- epilogue: per-lane 1/l (0 for masked query rows), LDS bounce per nd
  const int mo = maskg[b * SL + iw];
  const float fac = mo ? 0.f : 1.f / l_i;
  __syncthreads();  // all waves done reading KV before Osh overlay

#pragma unroll
  for (int nd = 0; nd < 2; ++nd) {
    // scatter acc into Osh [d_local][i_block] (2-way conflicts only)
#pragma unroll
    for (int e = 0; e < 16; ++e) {
      const int dl = (e & 3) + 8 * (e >> 2) + 4 * hf;
      Osh[dl * 256 + w * 32 + l5] = acc[nd][e] * fac;
    }
    __syncthreads();
    // coalesced store: 1KB contiguous per d-row, 8 rows per pass
#pragma unroll
    for (int pass = 0; pass < 4; ++pass) {
      const int row = pass * 8 + (t >> 6);
      const int i4 = (t & 63) * 4;
      const float4 o = *(const float4*)&Osh[row * 256 + i4];
      *(float4*)&outg[((size_t)b * DA + h * DH + nd * 32 + row) * SL + i0 + i4] = o;
    }
    __syncthreads();  // before next nd pass overwrites Osh
  }
}

// ---------------------------------------------------------------------------
extern "C" void kernel_launch(void* const* d_in, const int* in_sizes, int n_in,
                              void* d_out, int out_size, void* d_ws, size_t ws_size,
                              hipStream_t stream) {
  const float* q     = (const float*)d_in[0];
  const float* k_in  = (const float*)d_in[1];
  const float* v_in  = (const float*)d_in[2];
  const float* k_w   = (const float*)d_in[3];
  const float* k_b   = (const float*)d_in[4];
  const float* v_w   = (const float*)d_in[5];
  const float* v_b   = (const float*)d_in[6];
  const float* gamma = (const float*)d_in[7];
  const float* gbns  = (const float*)d_in[10];  // gbn_bias/gbn_m cancel under softmax
  const int*   mask  = (const int*)d_in[11];
  float* out = (float*)d_out;

  const size_t NEL = (size_t)BS * SL * DA;
  f16* kpw = (f16*)d_ws;        // k projection, [b][s][o], 16 MiB
  f16* vpw = kpw + NEL;         // v projection, [b][o][s], 16 MiB

  const size_t need = NEL * 2 * 4 + (size_t)DA * DA * 2 * 2;  // 64 MiB + 1 MiB
  if (ws_size >= need) {
    f16* Kt  = vpw + NEL;       // k_in transposed+converted, [b][s][c], 16 MiB
    f16* Vt  = Kt + NEL;        // v_in transposed+converted, [b][s][c], 16 MiB
    f16* kwh = Vt + NEL;        // k_w f16, [o][c]
    f16* vwh = kwh + (size_t)DA * DA;
    prep_kernel<<<dim3(2112), 256, 0, stream>>>(k_in, v_in, k_w, v_w, Kt, Vt, kwh, vwh);
    proj_gemm_all<<<dim3(32, BS, 2), 256, 0, stream>>>(kwh, vwh, Kt, Vt, k_b, v_b, kpw, vpw);
  } else {
    // fallback: old fused path (32 MiB workspace)
    fused_proj<0><<<dim3(4, 8, BS), 256, 0, stream>>>(k_w, k_in, k_b, kpw);
    fused_proj<1><<<dim3(8, 4, BS), 256, 0, stream>>>(v_w, v_in, v_b, vpw);
  }
  attn_kernel<<<dim3(BS * NH, SL / 256), 512, 0, stream>>>(q, kpw, vpw, gamma, gbns, mask, out);
}

// Round 6
// 235.034 us; speedup vs baseline: 1.6623x; 1.0072x over previous
//
#include <hip/hip_runtime.h>

typedef _Float16 f16;
typedef _Float16 h8_t __attribute__((ext_vector_type(8)));
typedef _Float16 h4_t __attribute__((ext_vector_type(4)));
typedef float f32x4 __attribute__((ext_vector_type(4)));
typedef float f32x16 __attribute__((ext_vector_type(16)));

#define BS 16
#define DA 512
#define SL 1024
#define NH 8
#define DH 64

// direct global->LDS DMA, 16B per lane. HW dest = wave-uniform base + lane*16,
// so lane i's lds pointer must equal base + i*16 (linear layout).
__device__ __forceinline__ void gload_lds16(const void* g, void* l) {
  __builtin_amdgcn_global_load_lds((const __attribute__((address_space(1))) void*)g,
                                   (__attribute__((address_space(3))) void*)l, 16, 0, 0);
}

// ---------------------------------------------------------------------------
// P0: prep pass (unchanged).
//  blocks [0,2048):   transpose+convert X [b][c][s] f32 -> Xt [b][s][c] f16
//  blocks [2048,2112): convert k_w / v_w f32 -> f16
// ---------------------------------------------------------------------------
__global__ __launch_bounds__(256) void prep_kernel(
    const float* __restrict__ k_in, const float* __restrict__ v_in,
    const float* __restrict__ k_w, const float* __restrict__ v_w,
    f16* __restrict__ Kt, f16* __restrict__ Vt,
    f16* __restrict__ kwh, f16* __restrict__ vwh) {
  const int blk = blockIdx.x;
  const int t = threadIdx.x;
  if (blk < 2048) {
    const int which = blk >> 10;        // 0: k_in, 1: v_in
    const int r = blk & 1023;
    const int b = r >> 6;               // 0..15
    const int c0 = ((r >> 3) & 7) * 64; // 8 c-tiles
    const int s0 = (r & 7) * 128;       // 8 s-tiles
    const float* src = which ? v_in : k_in;
    f16* dst = which ? Vt : Kt;
    __shared__ __align__(16) float Xf32[64 * 132];
#pragma unroll
    for (int p = 0; p < 8; ++p) {
      const int idx = p * 256 + t;
      const int cc = idx >> 5, s4 = (idx & 31) * 4;
      const float4 v = *(const float4*)&src[((size_t)b * DA + c0 + cc) * SL + s0 + s4];
      *(float4*)&Xf32[cc * 132 + s4] = v;
    }
    __syncthreads();
    const int srow = t >> 1, cb = (t & 1) * 32;
#pragma unroll
    for (int g = 0; g < 4; ++g) {
      h8_t h;
#pragma unroll
      for (int u = 0; u < 8; ++u) h[u] = (f16)Xf32[(cb + g * 8 + u) * 132 + srow];
      *(h8_t*)&dst[((size_t)b * SL + s0 + srow) * DA + c0 + cb + g * 8] = h;
    }
  } else {
    const int r = blk - 2048;           // 0..63
    const int wsel = r >> 5;            // 0: k_w, 1: v_w
    const float* src = wsel ? v_w : k_w;
    f16* dst = wsel ? vwh : kwh;
    const int base = (r & 31) * 8192;
#pragma unroll
    for (int p = 0; p < 4; ++p) {
      const int i = base + p * 2048 + t * 8;
      const float4 a = *(const float4*)&src[i];
      const float4 c = *(const float4*)&src[i + 4];
      h8_t h;
      h[0] = (f16)a.x; h[1] = (f16)a.y; h[2] = (f16)a.z; h[3] = (f16)a.w;
      h[4] = (f16)c.x; h[5] = (f16)c.y; h[6] = (f16)c.z; h[7] = (f16)c.w;
      *(h8_t*)&dst[i] = h;
    }
  }
}

// ---------------------------------------------------------------------------
// K1: merged projection GEMM, COUNTED-VMCNT pipeline (T3/T4). R5's version
// used __syncthreads() per K-step, whose implicit s_waitcnt vmcnt(0) drains
// the loads just issued for tile kt+1 -> full DMA latency exposed per step.
// New: raw s_barrier pair + s_waitcnt vmcnt(4): tile kt+1's 4 loads stay in
// flight across the whole compute body; only tile kt's loads are waited.
// vmcnt audit: the ONLY vmem ops before/inside the loop are the staging
// gload_lds (bias loads are post-loop; kernel args via SMEM=lgkm), so the
// counted N is exact. All barriers wave-uniform. sched_barrier(0) fences
// stop ds_reads hoisting above barrier-1 / sinking below barrier-2.
// grid (32 tiles, BS, 2 modes) = 1024 blocks = 4 blocks/CU (LDS 32KB dbuf).
// mode 0 (k-proj): A = kwh [o][c],    B = Kt[b] [s][c], out kp[b][s][o] + k_b(m)
// mode 1 (v-proj): A = Vt[b] [s][c],  B = vwh [o][c],   out vp[b][o][s] + v_b(n)
// ---------------------------------------------------------------------------
__global__ __launch_bounds__(256, 4) void proj_gemm_all(
    const f16* __restrict__ kwh, const f16* __restrict__ vwh,
    const f16* __restrict__ Kt, const f16* __restrict__ Vt,
    const float* __restrict__ k_b, const float* __restrict__ v_b,
    f16* __restrict__ kp, f16* __restrict__ vp) {
  __shared__ __align__(16) f16 LD[2][8192];  // [buf][Al 4096 | Bl 4096] f16
  const int mode = blockIdx.z;
  const int b = blockIdx.y;
  const int tx = blockIdx.x;                  // 32 tiles per (b, mode)
  const int m0 = (mode ? (tx >> 2) : (tx & 3)) * 128;
  const int n0 = (mode ? (tx & 3) : (tx >> 2)) * 128;
  const int t = threadIdx.x;
  const int lane = t & 63, w = t >> 6, lr = lane & 15, lq = lane >> 4;
  const int wm = (w >> 1) * 64, wn = (w & 1) * 64;

  const f16* Arow = (mode ? Vt + (size_t)b * SL * DA : kwh) + (size_t)m0 * DA;
  const f16* Brow = (mode ? vwh : Kt + (size_t)b * SL * DA) + (size_t)n0 * DA;

  const int rr = t >> 2;          // 0..63: tile row (lower half)
  const int c8 = (t & 3) * 8;     // f16 col within the 32-wide K-slice
  const int lo8 = t * 8;          // LDS f16 offset (linear: lane*16B)

  const f16* ga0 = Arow + (size_t)rr * DA + c8;
  const f16* ga1 = Arow + (size_t)(64 + rr) * DA + c8;
  const f16* gb0 = Brow + (size_t)rr * DA + c8;
  const f16* gb1 = Brow + (size_t)(64 + rr) * DA + c8;

  f32x4 acc[4][4] = {};

  // prologue: stage tile 0 into buf 0 (4 loads in flight; waited in iter 0)
  gload_lds16(ga0, &LD[0][0] + lo8);
  gload_lds16(ga1, &LD[0][2048] + lo8);
  gload_lds16(gb0, &LD[0][4096] + lo8);
  gload_lds16(gb1, &LD[0][6144] + lo8);
  ga0 += 32; ga1 += 32; gb0 += 32; gb1 += 32;

  for (int kt = 0; kt < 16; ++kt) {
    const int cur = kt & 1;
    if (kt < 15) {  // issue tile kt+1; it stays in flight across this body
      f16* nb = &LD[cur ^ 1][0];
      gload_lds16(ga0, nb + lo8);
      gload_lds16(ga1, nb + 2048 + lo8);
      gload_lds16(gb0, nb + 4096 + lo8);
      gload_lds16(gb1, nb + 6144 + lo8);
      ga0 += 32; ga1 += 32; gb0 += 32; gb1 += 32;
      asm volatile("s_waitcnt vmcnt(4)" ::: "memory");  // tile kt done (mine)
    } else {
      asm volatile("s_waitcnt vmcnt(0)" ::: "memory");  // last tile: drain
    }
    __builtin_amdgcn_s_barrier();        // everyone's tile-kt loads landed
    __builtin_amdgcn_sched_barrier(0);   // ds_reads must not hoist above

    const f16* Al = &LD[cur][0];
    const f16* Bl = &LD[cur][4096];
    h8_t af[4], bf[4];
#pragma unroll
    for (int i = 0; i < 4; ++i) af[i] = *(const h8_t*)&Al[(wm + i * 16 + lr) * 32 + lq * 8];
#pragma unroll
    for (int j = 0; j < 4; ++j) bf[j] = *(const h8_t*)&Bl[(wn + j * 16 + lr) * 32 + lq * 8];
    __builtin_amdgcn_s_setprio(1);
#pragma unroll
    for (int i = 0; i < 4; ++i)
#pragma unroll
      for (int j = 0; j < 4; ++j)
        acc[i][j] = __builtin_amdgcn_mfma_f32_16x16x32_f16(af[i], bf[j], acc[i][j], 0, 0, 0);
    __builtin_amdgcn_s_setprio(0);

    if (kt < 15) {
      __builtin_amdgcn_sched_barrier(0); // reads/MFMAs must not sink below
      __builtin_amdgcn_s_barrier();      // all reads of buf cur done ->
      __builtin_amdgcn_sched_barrier(0); // next iter may overwrite it
    }
  }

  // epilogue: D row = gm (4 consecutive per lane -> 8B f16 stores), col = gn
#pragma unroll
  for (int i = 0; i < 4; ++i) {
    const int gmb = m0 + wm + i * 16 + lq * 4;
    float bm[4] = {0.f, 0.f, 0.f, 0.f};
    if (mode == 0) {
      const float4 b4 = *(const float4*)&k_b[gmb];
      bm[0] = b4.x; bm[1] = b4.y; bm[2] = b4.z; bm[3] = b4.w;
    }
#pragma unroll
    for (int j = 0; j < 4; ++j) {
      const int gn = n0 + wn + j * 16 + lr;
      const float bn = mode ? v_b[gn] : 0.f;
      h4_t hv;
#pragma unroll
      for (int r = 0; r < 4; ++r) {
        const float val = acc[i][j][r] + (mode == 0 ? bm[r] : bn);
        hv[r] = (f16)val;
      }
      f16* dst = mode ? &vp[((size_t)b * DA + gn) * SL + gmb]
                      : &kp[((size_t)b * SL + gn) * DA + gmb];
      *(h4_t*)dst = hv;
    }
  }
}

// ---------------------------------------------------------------------------
// Fallback: fused transpose+projection kernel (small-workspace path only).
// ---------------------------------------------------------------------------
template <int MODE>
__global__ __launch_bounds__(256) void fused_proj(const float* __restrict__ Wg,
                                                  const float* __restrict__ Xin,
                                                  const float* __restrict__ bias,
                                                  f16* __restrict__ outg) {
  constexpr int MT = MODE ? SL : DA;
  constexpr int NT = MODE ? DA : SL;
  __shared__ f16 Wl[128 * 40];
  __shared__ f16 Xl[128 * 40];
  __shared__ float Xf32[32 * 132];
  const int b = blockIdx.z;
  const int m0 = blockIdx.x * 128;
  const int n0 = blockIdx.y * 128;
  const int o_base = MODE ? n0 : m0;
  const int s_base = MODE ? m0 : n0;
  const int t = threadIdx.x;
  const int w = t >> 6, lane = t & 63, lr = lane & 15, lq = lane >> 4;
  const int wm = (w >> 1) * 64, wn = (w & 1) * 64;

  f32x4 acc[4][4] = {};

  for (int kt = 0; kt < 16; ++kt) {
    const int c0 = kt * 32;
    __syncthreads();
#pragma unroll
    for (int p = 0; p < 4; ++p) {
      const int idx = p * 256 + t;
      const int row = idx >> 3, cq = (idx & 7) * 4;
      const float4 v = *(const float4*)&Wg[(size_t)(o_base + row) * DA + c0 + cq];
      h4_t hv;
      hv[0] = (f16)v.x; hv[1] = (f16)v.y; hv[2] = (f16)v.z; hv[3] = (f16)v.w;
      *(h4_t*)&Wl[row * 40 + cq] = hv;
    }
#pragma unroll
    for (int p = 0; p < 4; ++p) {
      const int idx = p * 256 + t;
      const int cc = idx >> 5, s4 = (idx & 31) * 4;
      const float4 v = *(const float4*)&Xin[((size_t)b * DA + c0 + cc) * SL + s_base + s4];
      *(float4*)&Xf32[cc * 132 + s4] = v;
    }
    __syncthreads();
    {
      const int srow = t >> 1, cb = (t & 1) * 16;
      h8_t lo, hi;
#pragma unroll
      for (int u = 0; u < 8; ++u) lo[u] = (f16)Xf32[(cb + u) * 132 + srow];
#pragma unroll
      for (int u = 0; u < 8; ++u) hi[u] = (f16)Xf32[(cb + 8 + u) * 132 + srow];
      *(h8_t*)&Xl[srow * 40 + cb] = lo;
      *(h8_t*)&Xl[srow * 40 + cb + 8] = hi;
    }
    __syncthreads();
    const f16* Alp = MODE ? Xl : Wl;
    const f16* Blp = MODE ? Wl : Xl;
    h8_t af[4], bf[4];
#pragma unroll
    for (int i = 0; i < 4; ++i) af[i] = *(const h8_t*)&Alp[(wm + i * 16 + lr) * 40 + lq * 8];
#pragma unroll
    for (int j = 0; j < 4; ++j) bf[j] = *(const h8_t*)&Blp[(wn + j * 16 + lr) * 40 + lq * 8];
#pragma unroll
    for (int i = 0; i < 4; ++i)
#pragma unroll
      for (int j = 0; j < 4; ++j)
        acc[i][j] = __builtin_amdgcn_mfma_f32_16x16x32_f16(af[i], bf[j], acc[i][j], 0, 0, 0);
  }

#pragma unroll
  for (int i = 0; i < 4; ++i) {
    const int gmb = m0 + wm + i * 16 + lq * 4;
    float bm[4] = {0.f, 0.f, 0.f, 0.f};
    if (MODE == 0) {
      const float4 b4 = *(const float4*)&bias[gmb];
      bm[0] = b4.x; bm[1] = b4.y; bm[2] = b4.z; bm[3] = b4.w;
    }
#pragma unroll
    for (int j = 0; j < 4; ++j) {
      const int gn = n0 + wn + j * 16 + lr;
      const float bn = (MODE == 1) ? bias[gn] : 0.f;
      h4_t hv;
#pragma unroll
      for (int r = 0; r < 4; ++r) {
        const float val = acc[i][j][r] + (MODE == 0 ? bm[r] : bn);
        hv[r] = (f16)val;
      }
      *(h4_t*)&outg[((size_t)b * NT + gn) * MT + gmb] = hv;
    }
  }
}

// ---------------------------------------------------------------------------
// K2: fused flash attention, 8-WAVE blocks (512 threads) — UNCHANGED from R5
// (verified 65.3 us, MfmaUtil 20.4, FETCH 39MB). Kept byte-identical so the
// proj-path delta this round is cleanly attributable.
// ---------------------------------------------------------------------------
__global__ __launch_bounds__(512, 4) void attn_kernel(
    const float* __restrict__ qg, const f16* __restrict__ kp, const f16* __restrict__ vp,
    const float* __restrict__ gamma, const float* __restrict__ gbns,
    const int* __restrict__ maskg, float* __restrict__ outg) {
  __shared__ __align__(16) char smem[36864 + 4096];
  f16* KV = (f16*)smem;       // 2 bufs x (K[64][72] + V[64][72]) f16
  float* Osh = (float*)smem;  // epilogue overlay [32 d][256 i] f32
  float* biasf = (float*)(smem + 36864);  // [SL] additive key-mask bias

  const int bh = blockIdx.x, b = bh >> 3, h = bh & 7;
  const int i0 = blockIdx.y * 256;
  const int t = threadIdx.x, w = t >> 6, lane = t & 63;
  const int l5 = lane & 31, hf = lane >> 5;
  const float scale = gamma[h] / gbns[h] * 1.44269504088896f;  // GBN scale * log2(e)
  const int iw = i0 + w * 32 + l5;  // this lane's query column

  // ---- Q fragments straight from global (B-operand: n=i, k=d)
  h8_t qf[4];
#pragma unroll
  for (int ks = 0; ks < 4; ++ks) {
    h8_t v;
#pragma unroll
    for (int u = 0; u < 8; ++u) {
      const int d = ks * 16 + hf * 8 + u;
      v[u] = (f16)(qg[((size_t)b * DA + h * DH + d) * SL + iw] * scale);
    }
    qf[ks] = v;
  }

  // ---- mask -> additive bias, staged to LDS once (512 threads x 2)
  {
    const int2 m2 = *(const int2*)&maskg[b * SL + t * 2];
    biasf[t * 2 + 0] = m2.x ? -1e9f : 0.f;
    biasf[t * 2 + 1] = m2.y ? -1e9f : 0.f;
  }

  const int srow = t >> 3;        // 0..63 with 512 threads
  const int c8 = (t & 7) * 8;

  // ---- stage tile 0 (K rows sigma-permuted: swap bits 2,3); 1 uint4/thread
  uint4 rk = *(const uint4*)&kp[((size_t)b * SL + srow) * DA + h * DH + c8];
  uint4 rv = *(const uint4*)&vp[((size_t)b * DA + h * DH + srow) * SL + c8];
  {
    f16* K0 = KV;
    f16* V0 = KV + 4608;
    const int rowp = (srow & ~12) | ((srow & 4) << 1) | ((srow & 8) >> 1);
    *(uint4*)&K0[rowp * 72 + c8] = rk;
    *(uint4*)&V0[srow * 72 + c8] = rv;
  }
  __syncthreads();  // KV tile 0 + bias table ready

  float m_i = -3e38f, l_i = 0.f;
  f32x16 acc[2] = {};  // [nd]: rows d = nd*32 + r(e,hf), col i = l5

  for (int jt = 0; jt < 16; ++jt) {
    const int j0 = jt * 64;
    const f16* Kc = KV + (jt & 1) * 9216;
    const f16* Vc = Kc + 4608;

    // prefetch next tile into regs (written at loop bottom; nothing below
    // forces a vmcnt drain before that write)
    if (jt < 15) {
      const int jn = j0 + 64;
      rk = *(const uint4*)&kp[((size_t)b * SL + jn + srow) * DA + h * DH + c8];
      rv = *(const uint4*)&vp[((size_t)b * DA + h * DH + srow) * SL + jn + c8];
    }

    // S^T = K * Q^T : rows = permuted K rows, cols = i
    f32x16 sa[2] = {};
    __builtin_amdgcn_s_setprio(1);
#pragma unroll
    for (int ks = 0; ks < 4; ++ks)
#pragma unroll
      for (int mj = 0; mj < 2; ++mj) {
        const h8_t kf = *(const h8_t*)&Kc[(mj * 32 + l5) * 72 + ks * 16 + hf * 8];
        sa[mj] = __builtin_amdgcn_mfma_f32_32x32x16_f16(kf, qf[ks], sa[mj], 0, 0, 0);
      }
    __builtin_amdgcn_s_setprio(0);

    // key-mask bias add (broadcast LDS reads; sigma-mapped j)
#pragma unroll
    for (int mj = 0; mj < 2; ++mj)
#pragma unroll
      for (int qq = 0; qq < 4; ++qq) {
        const float4 bq = *(const float4*)&biasf[j0 + mj * 32 + (qq >> 1) * 16 + hf * 8 + (qq & 1) * 4];
        sa[mj][qq * 4 + 0] += bq.x;
        sa[mj][qq * 4 + 1] += bq.y;
        sa[mj][qq * 4 + 2] += bq.z;
        sa[mj][qq * 4 + 3] += bq.w;
      }

    // ---- online softmax: tree max, defer-max (T13), 4-acc exp2 sums
    {
      float a[8];
#pragma unroll
      for (int u = 0; u < 8; ++u)
        a[u] = fmaxf(fmaxf(sa[0][u], sa[0][u + 8]), fmaxf(sa[1][u], sa[1][u + 8]));
      float mx = fmaxf(fmaxf(fmaxf(a[0], a[1]), fmaxf(a[2], a[3])),
                       fmaxf(fmaxf(a[4], a[5]), fmaxf(a[6], a[7])));
      mx = fmaxf(mx, __shfl_xor(mx, 32));
      if (!__all(mx - m_i <= 8.0f)) {  // skip rescale while tile max bounded
        const float mn = fmaxf(m_i, mx);
        const float alpha = __builtin_amdgcn_exp2f(m_i - mn);
        m_i = mn;
        l_i *= alpha;
#pragma unroll
        for (int nd = 0; nd < 2; ++nd)
#pragma unroll
          for (int e = 0; e < 16; ++e) acc[nd][e] *= alpha;
      }
      float r0 = 0.f, r1 = 0.f, r2 = 0.f, r3 = 0.f;
#pragma unroll
      for (int mj = 0; mj < 2; ++mj)
#pragma unroll
        for (int e = 0; e < 16; e += 4) {
          const float p0 = __builtin_amdgcn_exp2f(sa[mj][e + 0] - m_i);
          const float p1 = __builtin_amdgcn_exp2f(sa[mj][e + 1] - m_i);
          const float p2 = __builtin_amdgcn_exp2f(sa[mj][e + 2] - m_i);
          const float p3 = __builtin_amdgcn_exp2f(sa[mj][e + 3] - m_i);
          sa[mj][e + 0] = p0; sa[mj][e + 1] = p1;
          sa[mj][e + 2] = p2; sa[mj][e + 3] = p3;
          r0 += p0; r1 += p1; r2 += p2; r3 += p3;
        }
      float rs = (r0 + r1) + (r2 + r3);
      rs += __shfl_xor(rs, 32);
      l_i += rs;
    }

    // O^T += V^T * P^T : A = V^T[d][j] from LDS, B = P^T straight from regs
    // (sigma cancellation: B slot k holds logical j = k)
    __builtin_amdgcn_s_setprio(1);
#pragma unroll
    for (int jk = 0; jk < 4; ++jk) {
      const int mj = jk >> 1, g = jk & 1;
      h8_t pk;
#pragma unroll
      for (int u = 0; u < 8; ++u) pk[u] = (f16)sa[mj][g * 8 + u];
#pragma unroll
      for (int nd = 0; nd < 2; ++nd) {
        const h8_t vf = *(const h8_t*)&Vc[(nd * 32 + l5) * 72 + jk * 16 + hf * 8];
        acc[nd] = __builtin_amdgcn_mfma_f32_32x32x16_f16(vf, pk, acc[nd], 0, 0, 0);
      }
    }
    __builtin_amdgcn_s_setprio(0);

    // write prefetched tile into the other buffer; ONE barrier per tile
    if (jt < 15) {
      f16* Kn = KV + ((jt + 1) & 1) * 9216;
      f16* Vn = Kn + 4608;
      const int rowp = (srow & ~12) | ((srow & 4) << 1) | ((srow & 8) >> 1);
      *(uint4*)&Kn[rowp * 72 + c8] = rk;
      *(uint4*)&Vn[srow * 72 + c8] = rv;
      __syncthreads();
    }
  }

  // ---- epilogue: per-lane 1/l (0 for masked query rows), LDS bounce per nd
  const int mo = maskg[b * SL + iw];
  const float fac = mo ? 0.f : 1.f / l_i;
  __syncthreads();  // all waves done reading KV before Osh overlay

#pragma unroll
  for (int nd = 0; nd < 2; ++nd) {
    // scatter acc into Osh [d_local][i_block] (2-way conflicts only)
#pragma unroll
    for (int e = 0; e < 16; ++e) {
      const int dl = (e & 3) + 8 * (e >> 2) + 4 * hf;
      Osh[dl * 256 + w * 32 + l5] = acc[nd][e] * fac;
    }
    __syncthreads();
    // coalesced store: 1KB contiguous per d-row, 8 rows per pass
#pragma unroll
    for (int pass = 0; pass < 4; ++pass) {
      const int row = pass * 8 + (t >> 6);
      const int i4 = (t & 63) * 4;
      const float4 o = *(const float4*)&Osh[row * 256 + i4];
      *(float4*)&outg[((size_t)b * DA + h * DH + nd * 32 + row) * SL + i0 + i4] = o;
    }
    __syncthreads();  // before next nd pass overwrites Osh
  }
}

// ---------------------------------------------------------------------------
extern "C" void kernel_launch(void* const* d_in, const int* in_sizes, int n_in,
                              void* d_out, int out_size, void* d_ws, size_t ws_size,
                              hipStream_t stream) {
  const float* q     = (const float*)d_in[0];
  const float* k_in  = (const float*)d_in[1];
  const float* v_in  = (const float*)d_in[2];
  const float* k_w   = (const float*)d_in[3];
  const float* k_b   = (const float*)d_in[4];
  const float* v_w   = (const float*)d_in[5];
  const float* v_b   = (const float*)d_in[6];
  const float* gamma = (const float*)d_in[7];
  const float* gbns  = (const float*)d_in[10];  // gbn_bias/gbn_m cancel under softmax
  const int*   mask  = (const int*)d_in[11];
  float* out = (float*)d_out;

  const size_t NEL = (size_t)BS * SL * DA;
  f16* kpw = (f16*)d_ws;        // k projection, [b][s][o], 16 MiB
  f16* vpw = kpw + NEL;         // v projection, [b][o][s], 16 MiB

  const size_t need = NEL * 2 * 4 + (size_t)DA * DA * 2 * 2;  // 64 MiB + 1 MiB
  if (ws_size >= need) {
    f16* Kt  = vpw + NEL;       // k_in transposed+converted, [b][s][c], 16 MiB
    f16* Vt  = Kt + NEL;        // v_in transposed+converted, [b][s][c], 16 MiB
    f16* kwh = Vt + NEL;        // k_w f16, [o][c]
    f16* vwh = kwh + (size_t)DA * DA;
    prep_kernel<<<dim3(2112), 256, 0, stream>>>(k_in, v_in, k_w, v_w, Kt, Vt, kwh, vwh);
    proj_gemm_all<<<dim3(32, BS, 2), 256, 0, stream>>>(kwh, vwh, Kt, Vt, k_b, v_b, kpw, vpw);
  } else {
    // fallback: old fused path (32 MiB workspace)
    fused_proj<0><<<dim3(4, 8, BS), 256, 0, stream>>>(k_w, k_in, k_b, kpw);
    fused_proj<1><<<dim3(8, 4, BS), 256, 0, stream>>>(v_w, v_in, v_b, vpw);
  }
  attn_kernel<<<dim3(BS * NH, SL / 256), 512, 0, stream>>>(q, kpw, vpw, gamma, gbns, mask, out);
}